// Round 9
// baseline (308.582 us; speedup 1.0000x reference)
//
#include <hip/hip_runtime.h>
#include <math.h>
#include <stdint.h>

#define BATCH 2
#define SEQ   1024
#define EMB   1024
#define NH    16
#define DH    64
#define BSE   (BATCH*SEQ*EMB)   /* 2097152 elements per (B,S,E) tensor */
#define MROWS (BATCH*SEQ)       /* 2048 */

typedef unsigned short u16;
typedef __attribute__((ext_vector_type(8))) short short8;
typedef __attribute__((ext_vector_type(4))) float f32x4;

__device__ __forceinline__ float bf2f(u16 u) {
    return __uint_as_float(((unsigned int)u) << 16);
}
__device__ __forceinline__ u16 f2bf(float f) {
    unsigned int x = __float_as_uint(f);
    x += 0x7FFFu + ((x >> 16) & 1u);   // round-to-nearest-even
    return (u16)(x >> 16);
}

__device__ __forceinline__ void async_copy16(const void* g, void* l) {
    __builtin_amdgcn_global_load_lds(
        (const __attribute__((address_space(1))) unsigned int*)g,
        (__attribute__((address_space(3))) unsigned int*)l,
        16, 0, 0);
}

// log2(10000)/32 and 1/(2*pi)
#define ROPE_L2   0.4152410118609203f
#define INV2PI    0.15915494309189535f

// ---------------------------------------------------------------------------
// Pack: fp32 -> bf16, 24 slots of exactly 1M elems (no idle blocks).
// scaled=1: multiply by j2 = sin(2θ)-1. scaled=-1: zero-fill fp32 dst
// (folds the d_out memset for split-K atomics into this dispatch).
// grid = (1024, 24), 4 elems/thread.
// ---------------------------------------------------------------------------
struct PackArgs {
    const float* src[24];
    void*        dst[24];
    int          scaled[24];
};

__global__ __launch_bounds__(256) void pack_kernel(PackArgs pa, const float* __restrict__ theta)
{
    const int e = blockIdx.y;
    const size_t i = ((size_t)blockIdx.x * 256 + threadIdx.x) * 4;
    const int sm = pa.scaled[e];
    if (sm < 0) {                      // zero-fill fp32 (d_out)
        float4 z = {0.f, 0.f, 0.f, 0.f};
        *(float4*)((float*)pa.dst[e] + i) = z;
        return;
    }
    float sc = 1.0f;
    if (sm) sc = sinf(2.0f * theta[0]) - 1.0f;
    float4 v = *(const float4*)(pa.src[e] + i);
    ushort4 o;
    o.x = f2bf(v.x * sc); o.y = f2bf(v.y * sc);
    o.z = f2bf(v.z * sc); o.w = f2bf(v.w * sc);
    *(ushort4*)((u16*)pa.dst[e] + i) = o;
}

// ---------------------------------------------------------------------------
// MFMA bf16 GEMM with virtual K-concat (K=2048), up to 8 N-segments of 1024.
//   C[m][c] = sum_k A1[m][k]*Blo[c][k] + A2[m][k]*Bhi[c][k] + bias[c]
// mode: 0 = bf16 [m][c] store,
//       1 = fp32 atomicAdd [m][c] (split-K; bias added by ko==0 only),
//       2 = bf16 transposed store dst[b][c][s]  (V^T)
// SPLITK=1: one block does full K. SPLITK=2: blockIdx.z selects K-half.
// 128x128 tile, BK=32, 4 waves, 16x16x32 MFMA, global_load_lds width-16.
// ---------------------------------------------------------------------------
struct GemmArgs {
    const u16*   A1s[8];
    const u16*   A2s[8];
    const u16*   Blo[8];
    const u16*   Bhi[8];
    const float* bias[8];
    void*        dst[8];
    int          mode[8];
};

template<int SPLITK>
__global__ __launch_bounds__(256) void mfma_gemm(GemmArgs ga)
{
    __shared__ u16 sA[128][32];
    __shared__ u16 sB[128][32];

    const int t    = threadIdx.x;
    const int lane = t & 63;
    const int w    = t >> 6;
    const int wx   = w & 1;
    const int wy   = w >> 1;
    const int n0   = blockIdx.y * 128;   // n-tile = slow index
    const int m0   = blockIdx.x * 128;   // m-tile = fast index
    const int ko   = (SPLITK == 2) ? blockIdx.z : 0;
    const int seg  = n0 >> 10;
    const int nloc = n0 & 1023;

    const int srow = t >> 2;          // staging row within 64-row round
    const int sb   = (t & 3) * 16;    // staging byte offset within 64-B row

    f32x4 acc[4][4] = {};

    const char* A1 = (const char*)ga.A1s[seg];
    const char* A2 = (const char*)ga.A2s[seg];
    const char* Bl = (const char*)ga.Blo[seg];
    const char* Bh = (const char*)ga.Bhi[seg];
    if (SPLITK == 2 && ko) { A1 = A2; Bl = Bh; }

    const int frow = lane & 15;
    const int quad = lane >> 4;

    const int NKT = (SPLITK == 2) ? 32 : 64;
    for (int kt = 0; kt < NKT; ++kt) {
        const char* As = (SPLITK == 1 && (kt & 32)) ? A2 : A1;
        const char* Bs = (SPLITK == 1 && (kt & 32)) ? Bh : Bl;
        const size_t kbyte = (size_t)(kt & 31) * 64;

        __syncthreads();
        #pragma unroll
        for (int r = 0; r < 2; ++r) {
            const int row = r*64 + srow;
            const int ldsoff = (r*64 + w*16) * 64;
            async_copy16(As + (size_t)(m0 + row)*2048 + kbyte + sb,
                         (char*)&sA[0][0] + ldsoff);
            async_copy16(Bs + (size_t)(nloc + row)*2048 + kbyte + sb,
                         (char*)&sB[0][0] + ldsoff);
        }
        __syncthreads();

        short8 af[4], bfr[4];
        #pragma unroll
        for (int i = 0; i < 4; ++i)
            af[i] = *(const short8*)&sA[wy*64 + i*16 + frow][quad*8];
        #pragma unroll
        for (int j = 0; j < 4; ++j)
            bfr[j] = *(const short8*)&sB[wx*64 + j*16 + frow][quad*8];

        #pragma unroll
        for (int i = 0; i < 4; ++i)
            #pragma unroll
            for (int j = 0; j < 4; ++j)
                acc[i][j] = __builtin_amdgcn_mfma_f32_16x16x32_bf16(
                                af[i], bfr[j], acc[i][j], 0, 0, 0);
    }

    // ---- epilogue: C/D layout col=lane&15, row=quad*4+reg ----
    const float* bias = ga.bias[seg];
    const int mode = ga.mode[seg];

    #pragma unroll
    for (int j = 0; j < 4; ++j) {
        const int c = nloc + wx*64 + j*16 + frow;
        const float bv = (SPLITK == 2 && ko) ? 0.0f : bias[c];
        #pragma unroll
        for (int i = 0; i < 4; ++i) {
            #pragma unroll
            for (int reg = 0; reg < 4; ++reg) {
                const int m = m0 + wy*64 + i*16 + quad*4 + reg;
                const float val = acc[i][j][reg] + bv;
                if (mode == 1) {
                    if (SPLITK == 2)
                        atomicAdd((float*)ga.dst[seg] + (size_t)m*1024 + c, val);
                    else
                        ((float*)ga.dst[seg])[(size_t)m*1024 + c] = val;
                } else if (mode == 2) {
                    // V^T: [b][c][s], b = m>>10, s = m&1023
                    ((u16*)ga.dst[seg])[((size_t)(m >> 10) << 20) + (size_t)c*1024 + (m & 1023)] = f2bf(val);
                } else {
                    ((u16*)ga.dst[seg])[(size_t)m*1024 + c] = f2bf(val);
                }
            }
        }
    }
}

// ---------------------------------------------------------------------------
// MFMA flash attention with FUSED RoPE (q in registers; k during staging)
// and fixed-max softmax (scores are bounded magnitudes >= 0).
// Block = 4 waves; one (b,h), 64 q-rows (16/wave). K-tiles of 64 keys.
// K: register-staged (global -> rope -> ds_write, stride-72 swizzled rows).
// V: global_load_lds w/ XOR chunk swizzle (unchanged).
//   p = exp2(1.4427*mag), masked -> 0; l reduced once post-loop.
// ---------------------------------------------------------------------------
__global__ __launch_bounds__(256) void attn_mfma(
    const u16* __restrict__ qa, const u16* __restrict__ qb,
    const u16* __restrict__ ka, const u16* __restrict__ kb,
    const u16* __restrict__ vat, const u16* __restrict__ vbt,
    const float* __restrict__ thetas,
    u16* __restrict__ oa, u16* __restrict__ ob)
{
    __shared__ u16 sKa[64][72];     // stride 144B = 9*16B: aligned, 2-way banks
    __shared__ u16 sKb[64][72];
    __shared__ u16 sVa[64][64];
    __shared__ u16 sVb[64][64];
    __shared__ u16 sP[4][16][72];   // wave-private P

    const int t    = threadIdx.x;
    const int lane = t & 63;
    const int w    = t >> 6;
    const int L15  = lane & 15;
    const int quad = lane >> 4;

    // work-balanced mapping: bid<256 -> qt=15..8 ; bid>=256 -> qt=0..7
    const int bid  = blockIdx.x;
    const int aa   = (bid >> 5) & 7;
    const int qt   = (bid >> 8) ? aa : (15 - aa);
    const int bh   = bid & 31;
    const int h    = bh & 15;
    const int b    = bh >> 4;

    const float j2h = sinf(2.0f * thetas[h]) - 1.0f;

    // ---- Q fragments + fused rope (pairs (d,d+32) are (frag0[j],frag1[j])) ----
    const int   qrow  = qt*64 + w*16 + L15;               // seq position
    const size_t qbase = (size_t)(b*SEQ + qrow) * EMB + h*DH;
    short8 ra0 = *(const short8*)(qa + qbase + quad*8);
    short8 ra1 = *(const short8*)(qa + qbase + 32 + quad*8);
    short8 rb0 = *(const short8*)(qb + qbase + quad*8);
    short8 rb1 = *(const short8*)(qb + qbase + 32 + quad*8);
    short8 fqa[2], fqb[2], fjqb[2];
    #pragma unroll
    for (int j = 0; j < 8; ++j) {
        const int d = quad*8 + j;                          // 0..31
        const float invf = __builtin_amdgcn_exp2f(-(float)d * ROPE_L2) * INV2PI;
        float rev = (float)qrow * invf;
        rev -= floorf(rev);
        const float sn = __builtin_amdgcn_sinf(rev);
        const float cs = __builtin_amdgcn_cosf(rev);
        const float a1 = bf2f((u16)ra0[j]), a2 = bf2f((u16)ra1[j]);
        const float b1 = bf2f((u16)rb0[j]), b2 = bf2f((u16)rb1[j]);
        const float na1 = a1*cs - a2*sn, na2 = a2*cs + a1*sn;
        const float nb1 = b1*cs - b2*sn, nb2 = b2*cs + b1*sn;
        fqa[0][j]  = (short)f2bf(na1);       fqa[1][j]  = (short)f2bf(na2);
        fqb[0][j]  = (short)f2bf(nb1);       fqb[1][j]  = (short)f2bf(nb2);
        fjqb[0][j] = (short)f2bf(nb1 * j2h); fjqb[1][j] = (short)f2bf(nb2 * j2h);
    }

    f32x4 acc_a[4] = {};
    f32x4 acc_b[4] = {};
    float l_lane[4] = {0.f, 0.f, 0.f, 0.f};

    // V staging (async, swizzled) lane roles
    const int subrow = lane >> 3;
    const int g      = (lane & 7) ^ subrow;
    const int swz    = L15 & 7;        // read-side swizzle key

    // K staging lane roles: thread -> (row, chunk pair {glow, glow+4})
    const int krow  = t >> 2;                 // 0..63
    const int ku    = t & 3;
    const int glow  = (ku ^ (krow & 7)) & 3;  // low chunk: dims [8*glow, 8*glow+8)
    const int sl_lo = glow ^ (krow & 7);      // LDS slot of low chunk
    const int sl_hi = sl_lo ^ 4;              // LDS slot of high chunk
    float kinvf[8];
    #pragma unroll
    for (int j = 0; j < 8; ++j)
        kinvf[j] = __builtin_amdgcn_exp2f(-(float)(glow*8 + j) * ROPE_L2) * INV2PI;

    for (int kt = 0; kt <= qt; ++kt) {
        __syncthreads();
        // ---- V tiles: async global->LDS ----
        #pragma unroll
        for (int i = 0; i < 2; ++i) {
            const int row = w*16 + i*8 + subrow;
            const int ldsoff = (w*16 + i*8) * 128;
            const size_t vrow = (size_t)b*1048576 + (size_t)(h*64 + row)*1024 + kt*64;
            async_copy16((const char*)vat + vrow*2 + g*16,
                         (char*)&sVa[0][0] + ldsoff);
            async_copy16((const char*)vbt + vrow*2 + g*16,
                         (char*)&sVb[0][0] + ldsoff);
        }
        // ---- K tiles: registers -> rope -> LDS ----
        {
            const int   skey  = kt*64 + krow;             // seq position of key
            const size_t kadr = (size_t)(b*SEQ + skey) * EMB + h*DH + glow*8;
            short8 alo = *(const short8*)(ka + kadr);
            short8 ahi = *(const short8*)(ka + kadr + 32);
            short8 blo = *(const short8*)(kb + kadr);
            short8 bhi = *(const short8*)(kb + kadr + 32);
            short8 walo, wahi, wblo, wbhi;
            #pragma unroll
            for (int j = 0; j < 8; ++j) {
                float rev = (float)skey * kinvf[j];
                rev -= floorf(rev);
                const float sn = __builtin_amdgcn_sinf(rev);
                const float cs = __builtin_amdgcn_cosf(rev);
                const float a1 = bf2f((u16)alo[j]), a2 = bf2f((u16)ahi[j]);
                const float b1 = bf2f((u16)blo[j]), b2 = bf2f((u16)bhi[j]);
                walo[j] = (short)f2bf(a1*cs - a2*sn);
                wahi[j] = (short)f2bf(a2*cs + a1*sn);
                wblo[j] = (short)f2bf(b1*cs - b2*sn);
                wbhi[j] = (short)f2bf(b2*cs + b1*sn);
            }
            *(short8*)&sKa[krow][sl_lo*8] = walo;
            *(short8*)&sKa[krow][sl_hi*8] = wahi;
            *(short8*)&sKb[krow][sl_lo*8] = wblo;
            *(short8*)&sKb[krow][sl_hi*8] = wbhi;
        }
        __syncthreads();

        // ---- scores ----
        f32x4 sa[4] = {}, sb[4] = {};
        #pragma unroll
        for (int n = 0; n < 4; ++n) {
            const u16* rKa = &sKa[n*16 + L15][0];
            const u16* rKb = &sKb[n*16 + L15][0];
            short8 ka0 = *(const short8*)(rKa + (( quad      ^ swz) << 3));
            short8 ka1 = *(const short8*)(rKa + (((4 + quad) ^ swz) << 3));
            short8 kb0 = *(const short8*)(rKb + (( quad      ^ swz) << 3));
            short8 kb1 = *(const short8*)(rKb + (((4 + quad) ^ swz) << 3));
            sa[n] = __builtin_amdgcn_mfma_f32_16x16x32_bf16(fqa[0],  ka0, sa[n], 0, 0, 0);
            sa[n] = __builtin_amdgcn_mfma_f32_16x16x32_bf16(fqa[1],  ka1, sa[n], 0, 0, 0);
            sa[n] = __builtin_amdgcn_mfma_f32_16x16x32_bf16(fjqb[0], kb0, sa[n], 0, 0, 0);
            sa[n] = __builtin_amdgcn_mfma_f32_16x16x32_bf16(fjqb[1], kb1, sa[n], 0, 0, 0);
            sb[n] = __builtin_amdgcn_mfma_f32_16x16x32_bf16(fqa[0],  kb0, sb[n], 0, 0, 0);
            sb[n] = __builtin_amdgcn_mfma_f32_16x16x32_bf16(fqa[1],  kb1, sb[n], 0, 0, 0);
            sb[n] = __builtin_amdgcn_mfma_f32_16x16x32_bf16(fqb[0],  ka0, sb[n], 0, 0, 0);
            sb[n] = __builtin_amdgcn_mfma_f32_16x16x32_bf16(fqb[1],  ka1, sb[n], 0, 0, 0);
        }

        // ---- p = exp(mag) (fixed max = 0; causal mask -> 0) ----
        float p[4][4];
        if (kt == qt) {
            #pragma unroll
            for (int n = 0; n < 4; ++n)
                #pragma unroll
                for (int r = 0; r < 4; ++r) {
                    const float A = sa[n][r], B = sb[n][r];
                    const float mag = __builtin_amdgcn_sqrtf(A*A + B*B + 1e-8f) * 0.125f;
                    const bool masked = (n*16 + L15) > (w*16 + quad*4 + r);
                    p[n][r] = masked ? 0.0f
                                     : __builtin_amdgcn_exp2f(mag * 1.44269504f);
                }
        } else {
            #pragma unroll
            for (int n = 0; n < 4; ++n)
                #pragma unroll
                for (int r = 0; r < 4; ++r) {
                    const float A = sa[n][r], B = sb[n][r];
                    const float mag = __builtin_amdgcn_sqrtf(A*A + B*B + 1e-8f) * 0.125f;
                    p[n][r] = __builtin_amdgcn_exp2f(mag * 1.44269504f);
                }
        }
        #pragma unroll
        for (int r = 0; r < 4; ++r)
            l_lane[r] += (p[0][r] + p[1][r]) + (p[2][r] + p[3][r]);

        // ---- P -> LDS (wave-private), re-enter as A-operand ----
        #pragma unroll
        for (int n = 0; n < 4; ++n)
            #pragma unroll
            for (int r = 0; r < 4; ++r)
                sP[w][quad*4 + r][n*16 + L15] = f2bf(p[n][r]);

        short8 pf0 = *(const short8*)&sP[w][L15][quad*8];
        short8 pf1 = *(const short8*)&sP[w][L15][32 + quad*8];

        // ---- PV ----
        #pragma unroll
        for (int n = 0; n < 4; ++n) {
            const u16* rVa = &sVa[n*16 + L15][0];
            const u16* rVb = &sVb[n*16 + L15][0];
            short8 va0 = *(const short8*)(rVa + (( quad      ^ swz) << 3));
            short8 va1 = *(const short8*)(rVa + (((4 + quad) ^ swz) << 3));
            short8 vb0 = *(const short8*)(rVb + (( quad      ^ swz) << 3));
            short8 vb1 = *(const short8*)(rVb + (((4 + quad) ^ swz) << 3));
            acc_a[n] = __builtin_amdgcn_mfma_f32_16x16x32_bf16(pf0, va0, acc_a[n], 0, 0, 0);
            acc_a[n] = __builtin_amdgcn_mfma_f32_16x16x32_bf16(pf1, va1, acc_a[n], 0, 0, 0);
            acc_b[n] = __builtin_amdgcn_mfma_f32_16x16x32_bf16(pf0, vb0, acc_b[n], 0, 0, 0);
            acc_b[n] = __builtin_amdgcn_mfma_f32_16x16x32_bf16(pf1, vb1, acc_b[n], 0, 0, 0);
        }
    }

    // ---- final l reduction (row lives across the 16 lanes of a quad) ----
    float inv[4];
    #pragma unroll
    for (int r = 0; r < 4; ++r) {
        float l = l_lane[r];
        #pragma unroll
        for (int off = 8; off >= 1; off >>= 1)
            l += __shfl_xor(l, off, 64);
        inv[r] = 1.0f / l;
    }

    // ---- write out (C layout: row=quad*4+reg, col=n*16+L15) ----
    #pragma unroll
    for (int reg = 0; reg < 4; ++reg) {
        const size_t tok = (size_t)(b*SEQ + qt*64 + w*16 + quad*4 + reg);
        #pragma unroll
        for (int n = 0; n < 4; ++n) {
            const size_t idx = tok*EMB + h*DH + n*16 + L15;
            oa[idx] = f2bf(acc_a[n][reg] * inv[reg]);
            ob[idx] = f2bf(acc_b[n][reg] * inv[reg]);
        }
    }
}

// ---------------------------------------------------------------------------
extern "C" void kernel_launch(void* const* d_in, const int* in_sizes, int n_in,
                              void* d_out, int out_size, void* d_ws, size_t ws_size,
                              hipStream_t stream)
{
    const float* x_q_a  = (const float*)d_in[0];
    const float* x_q_b  = (const float*)d_in[1];
    const float* x_kv_a = (const float*)d_in[2];
    const float* x_kv_b = (const float*)d_in[3];
    const float* theta    = (const float*)d_in[5];
    const float* thetas_h = (const float*)d_in[6];
    const float* q_wa = (const float*)d_in[7];
    const float* q_wb = (const float*)d_in[8];
    const float* q_ba = (const float*)d_in[9];
    const float* q_bb = (const float*)d_in[10];
    const float* k_wa = (const float*)d_in[11];
    const float* k_wb = (const float*)d_in[12];
    const float* k_ba = (const float*)d_in[13];
    const float* k_bb = (const float*)d_in[14];
    const float* v_wa = (const float*)d_in[15];
    const float* v_wb = (const float*)d_in[16];
    const float* v_ba = (const float*)d_in[17];
    const float* v_bb = (const float*)d_in[18];
    const float* o_wa = (const float*)d_in[19];
    const float* o_wb = (const float*)d_in[20];
    const float* o_ba = (const float*)d_in[21];
    const float* o_bb = (const float*)d_in[22];

    u16* W = (u16*)d_ws;
    const size_t XN = (size_t)BSE;
    const size_t WN = (size_t)EMB*EMB;
    u16* xq_a16  = W;
    u16* xq_b16  = W + XN;
    u16* xkv_a16 = W + 2*XN;
    u16* xkv_b16 = W + 3*XN;
    u16* wbase   = W + 4*XN;
    u16* q_wa16  = wbase;
    u16* q_wb16  = wbase + WN;
    u16* k_wa16  = wbase + 2*WN;
    u16* k_wb16  = wbase + 3*WN;
    u16* v_wa16  = wbase + 4*WN;
    u16* v_wb16  = wbase + 5*WN;
    u16* o_wa16  = wbase + 6*WN;
    u16* o_wb16  = wbase + 7*WN;
    u16* q_wbs16 = wbase + 8*WN;
    u16* k_wbs16 = wbase + 9*WN;
    u16* v_wbs16 = wbase + 10*WN;
    u16* o_wbs16 = wbase + 11*WN;
    u16* qkv     = wbase + 12*WN;
    u16* qa16 = qkv;
    u16* qb16 = qkv + XN;
    u16* ka16 = qkv + 2*XN;
    u16* kb16 = qkv + 3*XN;
    u16* vat16 = qkv + 4*XN;   // transposed [b][c][s]
    u16* vbt16 = qkv + 5*XN;
    u16* ao16 = xq_a16;        // alias: xq region free after QKV GEMM
    u16* bo16 = xq_b16;

    float* out_a = (float*)d_out;
    float* out_b = out_a + (size_t)BSE;

    // ---- 1. pack to bf16 + zero d_out (24 fully-active slots of 1M elems) ----
    PackArgs pa;
    int si = 0;
    auto add = [&](const void* s, void* d, int scaled, int chunks) {
        for (int c = 0; c < chunks; ++c) {
            pa.src[si] = (const float*)s + (size_t)c * WN;
            pa.dst[si] = (scaled < 0) ? (void*)((float*)d + (size_t)c * WN)
                                      : (void*)((u16*)d + (size_t)c * WN);
            pa.scaled[si] = scaled;
            ++si;
        }
    };
    add(x_q_a,  xq_a16,  0, 2);
    add(x_q_b,  xq_b16,  0, 2);
    add(x_kv_a, xkv_a16, 0, 2);
    add(x_kv_b, xkv_b16, 0, 2);
    add(q_wa, q_wa16, 0, 1);  add(q_wb, q_wb16, 0, 1);
    add(k_wa, k_wa16, 0, 1);  add(k_wb, k_wb16, 0, 1);
    add(v_wa, v_wa16, 0, 1);  add(v_wb, v_wb16, 0, 1);
    add(o_wa, o_wa16, 0, 1);  add(o_wb, o_wb16, 0, 1);
    add(q_wb, q_wbs16, 1, 1); add(k_wb, k_wbs16, 1, 1);
    add(v_wb, v_wbs16, 1, 1); add(o_wb, o_wbs16, 1, 1);
    add(nullptr, d_out, -1, 4);     // zero 4M fp32 of d_out for split-K atomics
    pack_kernel<<<dim3(WN/1024, 24), 256, 0, stream>>>(pa, theta);

    // ---- 2. QKV projections: ONE dispatch, 6 segments ----
    GemmArgs g12;
    const u16* a1s[6] = { xq_a16, xq_a16, xkv_a16, xkv_a16, xkv_a16, xkv_a16 };
    const u16* a2s[6] = { xq_b16, xq_b16, xkv_b16, xkv_b16, xkv_b16, xkv_b16 };
    const u16* blo[6] = { q_wa16, q_wb16, k_wa16, k_wb16, v_wa16, v_wb16 };
    const u16* bhi[6] = { q_wbs16, q_wa16, k_wbs16, k_wa16, v_wbs16, v_wa16 };
    const float* bia[6] = { q_ba, q_bb, k_ba, k_bb, v_ba, v_bb };
    void* dsts[6] = { qa16, qb16, ka16, kb16, vat16, vbt16 };
    const int modes[6] = { 0, 0, 0, 0, 2, 2 };
    for (int s = 0; s < 6; ++s) {
        g12.A1s[s] = a1s[s]; g12.A2s[s] = a2s[s];
        g12.Blo[s] = blo[s]; g12.Bhi[s] = bhi[s];
        g12.bias[s] = bia[s]; g12.dst[s] = dsts[s]; g12.mode[s] = modes[s];
    }
    for (int s = 6; s < 8; ++s) {
        g12.A1s[s] = a1s[0]; g12.A2s[s] = a2s[0];
        g12.Blo[s] = blo[0]; g12.Bhi[s] = bhi[0];
        g12.bias[s] = bia[0]; g12.dst[s] = dsts[0]; g12.mode[s] = 0;
    }
    mfma_gemm<1><<<dim3(MROWS/128, 48), 256, 0, stream>>>(g12);

    // ---- 3. attention (MFMA flash, fused rope, fixed-max softmax) ----
    attn_mfma<<<BATCH*NH*(SEQ/64), 256, 0, stream>>>(qa16, qb16, ka16, kb16,
                                                     vat16, vbt16, thetas_h, ao16, bo16);

    // ---- 4. output projection: split-K=2, fp32 atomic accumulation ----
    GemmArgs g3;
    for (int s = 0; s < 8; ++s) {
        g3.A1s[s] = ao16; g3.A2s[s] = bo16;
        g3.Blo[s] = o_wa16; g3.Bhi[s] = o_wbs16;
        g3.bias[s] = o_ba; g3.dst[s] = out_a; g3.mode[s] = 1;
    }
    g3.Blo[1] = o_wb16; g3.Bhi[1] = o_wa16; g3.bias[1] = o_bb; g3.dst[1] = out_b;
    mfma_gemm<2><<<dim3(MROWS/128, 16, 2), 256, 0, stream>>>(g3);
}